// Round 22
// baseline (104.061 us; speedup 1.0000x reference)
//
#include <hip/hip_runtime.h>
#include <hip/hip_bf16.h>
#include <hip/hip_fp16.h>

#define NROWS 32768
#define HH 128
#define ENTN 50000
#define PEBLKS 391

typedef _Float16 f16x8 __attribute__((ext_vector_type(8)));
typedef __fp16 fp16x2 __attribute__((ext_vector_type(2)));
typedef float f32x4 __attribute__((ext_vector_type(4)));
typedef float f32x16 __attribute__((ext_vector_type(16)));

// ws byte offsets
#define OFF_PEB 0                       // u32 [50000][8jb][2h][4q][2pr] packed {f16 K*m | f16 K*g} (25.6 MB)
#define OFF_WF  25600000                // f16 [8jb][8kt][64][8] acc-weight frags, K-scaled (65536 B)
#define OFF_POPK (OFF_WF + 65536)       // u32 [5][8jb][2h][4q][2pr] packed f16 {K*m,K*g} (2560 B)

#define KM 2.8853901f
#define KG (-1.4426950f)
#define RSTR 272                        // acc LDS row stride (256 + 16 pad)
#define HALF (32 * RSTR)                // 8704 B per parity buffer
#define TILEB (2 * HALF)                // tile B base offset in Abuf

#if defined(__has_builtin)
#if __has_builtin(__builtin_amdgcn_exp2f)
#define FEXP2(x) __builtin_amdgcn_exp2f(x)
#endif
#endif
#ifndef FEXP2
__device__ __forceinline__ float __fexp2_asm(float x) {
    float r; asm("v_exp_f32 %0, %1" : "=v"(r) : "v"(x)); return r;
}
#define FEXP2(x) __fexp2_asm(x)
#endif

__device__ __forceinline__ unsigned pk2(float a, float b) {
    fp16x2 h = __builtin_amdgcn_cvt_pkrtz(a, b);
    unsigned u; __builtin_memcpy(&u, &h, 4); return u;
}
__device__ __forceinline__ unsigned pk2rtn(float a, float b) {
    _Float16 lo = (_Float16)a, hi = (_Float16)b;
    unsigned short ul, uh;
    __builtin_memcpy(&ul, &lo, 2); __builtin_memcpy(&uh, &hi, 2);
    return (unsigned)ul | ((unsigned)uh << 16);
}

// ---------------- merged pe + prep (2-kernel plan, no PEF table) ----------------
// blocks [0,391): PEB via MFMA, frags self-built ONCE per block, 4x32 entities/block
// blocks [391,522): WF / POPK / out-tail
__global__ __launch_bounds__(256, 4)
void pe_prep_kernel(const float* __restrict__ ent_table,
                    const float* __restrict__ op_table,
                    const float* __restrict__ non_table,
                    const float* __restrict__ Wm, const float* __restrict__ bm,
                    const float* __restrict__ Wg, const float* __restrict__ bg,
                    char* __restrict__ ws, float* __restrict__ out) {
    int blk = blockIdx.x;
    int tid = threadIdx.x;
    if (blk < PEBLKS) {
        char* PEB = ws + OFF_PEB;
        int w = tid >> 6, l = tid & 63, lr = l & 15, lg = (l >> 4) & 3;

        // self-build ent-path frags (j-perm layout), same values as the old PEF path
        f16x8 WB[4][4];
        #pragma unroll
        for (int u = 0; u < 4; ++u) {
            int jbf = 4 * w + u;
            int j = (jbf >> 1) * 32 + 8 * (lr >> 2) + 4 * (jbf & 1) + (lr & 3);
            int c = j >> 1, p = j & 1;
            const float* Wrow = (p ? Wg : Wm) + (size_t)c * 384 + 128;
            #pragma unroll
            for (int kt = 0; kt < 4; ++kt) {
                const float4* s = (const float4*)(Wrow + kt * 32 + lg * 8);
                float4 a0 = s[0], a1 = s[1];
                _Float16 h8[8] = {(_Float16)a0.x, (_Float16)a0.y, (_Float16)a0.z, (_Float16)a0.w,
                                  (_Float16)a1.x, (_Float16)a1.y, (_Float16)a1.z, (_Float16)a1.w};
                WB[u][kt] = *(f16x8*)h8;
            }
        }

        for (int it = 0; it < 4; ++it) {
            int e0 = blk * 128 + it * 32;
            f32x4 C[2][4];
            #pragma unroll
            for (int rt = 0; rt < 2; ++rt)
                #pragma unroll
                for (int u = 0; u < 4; ++u) C[rt][u] = (f32x4){0.f, 0.f, 0.f, 0.f};

            #pragma unroll
            for (int kt = 0; kt < 4; ++kt) {
                #pragma unroll
                for (int rt = 0; rt < 2; ++rt) {
                    int e = e0 + rt * 16 + lr;
                    if (e >= ENTN) e = ENTN - 1;
                    const float4* s = (const float4*)(ent_table + (size_t)e * HH + kt * 32 + lg * 8);
                    float4 v0 = s[0], v1 = s[1];
                    unsigned u4[4] = {pk2(v0.x, v0.y), pk2(v0.z, v0.w),
                                      pk2(v1.x, v1.y), pk2(v1.z, v1.w)};
                    f16x8 A; __builtin_memcpy(&A, u4, 16);
                    #pragma unroll
                    for (int u = 0; u < 4; ++u)
                        C[rt][u] = __builtin_amdgcn_mfma_f32_16x16x32_f16(WB[u][kt], A, C[rt][u], 0, 0, 0);
                }
            }
            #pragma unroll
            for (int rt = 0; rt < 2; ++rt) {
                int e = e0 + rt * 16 + lr;
                if (e < ENTN) {
                    #pragma unroll
                    for (int u = 0; u < 4; ++u) {
                        int jb2 = 2 * w + (u >> 1);
                        uint2 st;
                        st.x = pk2(C[rt][u][0] * KM, C[rt][u][1] * KG);
                        st.y = pk2(C[rt][u][2] * KM, C[rt][u][3] * KG);
                        *(uint2*)(PEB + (size_t)e * 512 + jb2 * 64 + (u & 1) * 32 + lg * 8) = st;
                    }
                }
            }
        }
    } else {
        int idx = (blk - PEBLKS) * 256 + tid;
        if (idx < 32768) {                       // WF: 32x32 acc-path frags, K-scaled
            int e = idx;
            int jj = e & 7, l = (e >> 3) & 63, kt = (e >> 9) & 7, jb = e >> 12;
            int j = jb * 32 + (l & 31);
            int c = j >> 1, p = j & 1;
            int k = kt * 16 + (l >> 5) * 8 + jj;
            const float* Wrow = p ? (Wg + (size_t)c * 384) : (Wm + (size_t)c * 384);
            ((_Float16*)(ws + OFF_WF))[e] = (_Float16)(Wrow[256 + k] * (p ? KG : KM));
        } else if (idx < 33408) {                // POPK: packed f16 {K*m, K*g} per u32
            int t2 = idx - 32768;
            int pr = t2 & 1, q = (t2 >> 1) & 3, h = (t2 >> 3) & 1, jb = (t2 >> 4) & 7, o = t2 >> 7;
            int j0 = jb * 32 + 8 * q + 4 * h + 2 * pr;
            int c = j0 >> 1;
            float sm = bm[c], sg = bg[c];
            const float* Wrm = Wm + (size_t)c * 384;
            const float* Wrg = Wg + (size_t)c * 384;
            for (int i = 0; i < 128; ++i) {
                float ov = op_table[o * HH + i];
                sm += ov * Wrm[i];
                sg += ov * Wrg[i];
            }
            ((unsigned*)(ws + OFF_POPK))[t2] = pk2rtn(sm * KM, sg * KG);
        } else if (idx < 33536) {
            int j = idx - 33408;
            out[(size_t)NROWS * HH + j] = non_table[j];
        }
    }
}

// ---------------- fused 17-step chain: 32x32x16 MFMA, DUAL 32-row tiles (v21 verbatim) ----------------
__global__ __launch_bounds__(512, 4)
void chain_kernel(const float* __restrict__ ent_table,
                  const int* __restrict__ ops_idx,
                  const int* __restrict__ ents_idx,
                  const int* __restrict__ left_idx,
                  const char* __restrict__ ws, float* __restrict__ out) {
    __shared__ char Abuf[4 * HALF];    // [2tile][2p][32r][272B]
    __shared__ unsigned eo[17 * 64];   // [t][rr]: (e<<9) | o, rr in 0..63
    __shared__ unsigned popk[640];

    const char* PEBc = ws + OFF_PEB;
    const f16x8* WFp = (const f16x8*)(ws + OFF_WF);
    const unsigned* POPKg = (const unsigned*)(ws + OFF_POPK);

    int tid = threadIdx.x;
    int jb = tid >> 6, l = tid & 63, r = l & 31, h = l >> 5;
    int row0 = blockIdx.x * 64;

    for (int i = tid; i < 17 * 64; i += 512) {
        int t = i >> 6, rr = i & 63;
        unsigned e, o;
        if (t < 16) {
            e = ents_idx[(row0 + rr) * 17 + 15 - t];
            o = ops_idx[(row0 + rr) * 16 + 15 - t];
        } else {
            e = left_idx[row0 + rr];
            o = 4;
        }
        eo[i] = (e << 9) | o;
    }
    for (int i = tid; i < 640; i += 512) popk[i] = POPKg[i];

    f16x8 WH[8];
    #pragma unroll
    for (int kt = 0; kt < 8; ++kt)
        WH[kt] = WFp[(jb * 8 + kt) * 64 + l];

    {   // acc0 init -> parity 0 of both tiles
        int rr = tid >> 3, sub = tid & 7;
        int e = ents_idx[(row0 + rr) * 17 + 16];
        const float4* src = (const float4*)(ent_table + (size_t)e * HH + sub * 16);
        float4 a = src[0], b = src[1], c2 = src[2], d2 = src[3];
        uint4 lo, hi;
        lo.x = pk2(a.x, a.y);  lo.y = pk2(a.z, a.w);
        lo.z = pk2(b.x, b.y);  lo.w = pk2(b.z, b.w);
        hi.x = pk2(c2.x, c2.y); hi.y = pk2(c2.z, c2.w);
        hi.z = pk2(d2.x, d2.y); hi.w = pk2(d2.z, d2.w);
        char* dst = Abuf + (rr >> 5) * TILEB + (rr & 31) * RSTR + sub * 32;
        *(uint4*)dst = lo;
        *(uint4*)(dst + 16) = hi;
    }
    __syncthreads();

    int rb = r * RSTR + h * 16;              // B-frag read base (+ kt*32)
    int wb = r * RSTR + jb * 32 + h * 4;     // acc write base (+ q*8)
    const char* pebBase = PEBc + jb * 64 + h * 32;
    const char* popkB = (const char*)popk + jb * 64 + h * 32;
    const unsigned* eoB = eo + r;

    unsigned vaA = eoB[0], vaB = eoB[32];
    uint4 pa0A = *(const uint4*)(pebBase + (vaA & 0xFFFFFE00u));
    uint4 pa1A = *(const uint4*)(pebBase + (vaA & 0xFFFFFE00u) + 16);
    uint4 pa0B = *(const uint4*)(pebBase + (vaB & 0xFFFFFE00u));
    uint4 pa1B = *(const uint4*)(pebBase + (vaB & 0xFFFFFE00u) + 16);

#define TILE_BODY(VA, PA0, PA1, TOFF, ROWOFF, RD, WR, FINAL)                    \
    {                                                                           \
        const char* pq = popkB + ((VA) & 7u) * 512;                             \
        uint4 po0 = *(const uint4*)(pq);                                        \
        uint4 po1 = *(const uint4*)(pq + 16);                                   \
        unsigned pe_u[8] = {(PA0).x, (PA0).y, (PA0).z, (PA0).w,                 \
                            (PA1).x, (PA1).y, (PA1).z, (PA1).w};                \
        unsigned po_u[8] = {po0.x, po0.y, po0.z, po0.w,                         \
                            po1.x, po1.y, po1.z, po1.w};                        \
        f32x16 C;                                                               \
        _Pragma("unroll")                                                       \
        for (int q = 0; q < 4; ++q)                                             \
            _Pragma("unroll")                                                   \
            for (int pr = 0; pr < 2; ++pr) {                                    \
                int u = q * 2 + pr;                                             \
                __half2 sa = *(const __half2*)&pe_u[u];                         \
                __half2 sb = *(const __half2*)&po_u[u];                         \
                __half2 s = __hadd2(sa, sb);                                    \
                C[4 * q + 2 * pr] = __low2float(s);                             \
                C[4 * q + 2 * pr + 1] = __high2float(s);                        \
            }                                                                   \
        _Pragma("unroll")                                                       \
        for (int kt = 0; kt < 8; ++kt) {                                        \
            f16x8 A = *(const f16x8*)(Abuf + (TOFF) + rb + (RD) + kt * 32);     \
            C = __builtin_amdgcn_mfma_f32_32x32x16_f16(WH[kt], A, C, 0, 0, 0);  \
        }                                                                       \
        _Pragma("unroll")                                                       \
        for (int q = 0; q < 4; ++q) {                                           \
            float ov[2];                                                        \
            _Pragma("unroll")                                                   \
            for (int pr = 0; pr < 2; ++pr) {                                    \
                float m = C[4 * q + 2 * pr];                                    \
                float g = C[4 * q + 2 * pr + 1];                                \
                float em = FEXP2(m), eg = FEXP2(g);                             \
                ov[pr] = (em - 1.f) * __builtin_amdgcn_rcpf((em + 1.f) * (1.f + eg)); \
            }                                                                   \
            if (FINAL) {                                                        \
                *(float2*)(out + (size_t)(row0 + (ROWOFF) + r) * HH             \
                           + jb * 16 + 4 * q + 2 * h) = make_float2(ov[0], ov[1]); \
            } else {                                                            \
                *(unsigned*)(Abuf + (TOFF) + wb + (WR) + q * 8) = pk2(ov[0], ov[1]); \
            }                                                                   \
        }                                                                       \
    }

#define DO_STEP(T, RD, WR, FINAL)                                               \
    {                                                                           \
        uint4 npa0A, npa1A, npa0B, npa1B; unsigned nvaA = 0, nvaB = 0;          \
        if (!(FINAL)) {                                                         \
            nvaA = eoB[((T) + 1) * 64];                                         \
            nvaB = eoB[((T) + 1) * 64 + 32];                                    \
            npa0A = *(const uint4*)(pebBase + (nvaA & 0xFFFFFE00u));            \
            npa1A = *(const uint4*)(pebBase + (nvaA & 0xFFFFFE00u) + 16);       \
            npa0B = *(const uint4*)(pebBase + (nvaB & 0xFFFFFE00u));            \
            npa1B = *(const uint4*)(pebBase + (nvaB & 0xFFFFFE00u) + 16);       \
        }                                                                       \
        TILE_BODY(vaA, pa0A, pa1A, 0, 0, RD, WR, FINAL)                         \
        TILE_BODY(vaB, pa0B, pa1B, TILEB, 32, RD, WR, FINAL)                    \
        __syncthreads();                                                        \
        if (!(FINAL)) {                                                         \
            pa0A = npa0A; pa1A = npa1A; vaA = nvaA;                             \
            pa0B = npa0B; pa1B = npa1B; vaB = nvaB;                             \
        }                                                                       \
    }

    for (int tb = 0; tb < 8; ++tb) {
        int t0 = 2 * tb;
        DO_STEP(t0, 0, HALF, 0)
        DO_STEP(t0 + 1, HALF, 0, 0)
    }
    DO_STEP(16, 0, HALF, 1)
#undef DO_STEP
#undef TILE_BODY
}

extern "C" void kernel_launch(void* const* d_in, const int* in_sizes, int n_in,
                              void* d_out, int out_size, void* d_ws, size_t ws_size,
                              hipStream_t stream) {
    const float* ent_table = (const float*)d_in[0];
    const float* op_table  = (const float*)d_in[1];
    const float* non_table = (const float*)d_in[2];
    const float* Wm        = (const float*)d_in[3];
    const float* bm        = (const float*)d_in[4];
    const float* Wg        = (const float*)d_in[5];
    const float* bg        = (const float*)d_in[6];
    const int* ops_idx     = (const int*)d_in[7];
    const int* ents_idx    = (const int*)d_in[8];
    const int* left_idx    = (const int*)d_in[9];
    float* out = (float*)d_out;
    char* ws = (char*)d_ws;

    pe_prep_kernel<<<PEBLKS + 131, 256, 0, stream>>>(ent_table, op_table, non_table,
                                                     Wm, bm, Wg, bg, ws, out);
    chain_kernel<<<NROWS / 64, 512, 0, stream>>>(ent_table, ops_idx, ents_idx,
                                                 left_idx, ws, out);
}

// Round 24
// 103.602 us; speedup vs baseline: 1.0044x; 1.0044x over previous
//
#include <hip/hip_runtime.h>
#include <hip/hip_bf16.h>
#include <hip/hip_fp16.h>

#define NROWS 32768
#define HH 128
#define ENTN 50000

typedef _Float16 f16x8 __attribute__((ext_vector_type(8)));
typedef __fp16 fp16x2 __attribute__((ext_vector_type(2)));
typedef float f32x16 __attribute__((ext_vector_type(16)));

// ws byte offsets
#define OFF_EB   0                      // f16 [50000][128] (12.8 MB)
#define OFF_WF   12800000               // f16 [8jb][8kt][64][8] acc-weight frags, K-scaled (65536 B)
#define OFF_WEF  (OFF_WF + 65536)       // f16 [8jb][8kt][64][8] ent-weight frags, K-scaled (65536 B)
#define OFF_POPK (OFF_WEF + 65536)      // u32 [5][8jb][2h][4q][2pr] packed f16 {K*m,K*g} (2560 B)

#define KM 2.8853901f
#define KG (-1.4426950f)
#define RSTR 272                        // LDS row stride (256 + 16 pad)
#define HALF (32 * RSTR)                // 8704 B per parity buffer

#if defined(__has_builtin)
#if __has_builtin(__builtin_amdgcn_exp2f)
#define FEXP2(x) __builtin_amdgcn_exp2f(x)
#endif
#endif
#ifndef FEXP2
__device__ __forceinline__ float __fexp2_asm(float x) {
    float r; asm("v_exp_f32 %0, %1" : "=v"(r) : "v"(x)); return r;
}
#define FEXP2(x) __fexp2_asm(x)
#endif

__device__ __forceinline__ unsigned pk2(float a, float b) {
    fp16x2 h = __builtin_amdgcn_cvt_pkrtz(a, b);
    unsigned u; __builtin_memcpy(&u, &h, 4); return u;
}
__device__ __forceinline__ unsigned pk2rtn(float a, float b) {
    _Float16 lo = (_Float16)a, hi = (_Float16)b;
    unsigned short ul, uh;
    __builtin_memcpy(&ul, &lo, 2); __builtin_memcpy(&uh, &hi, 2);
    return (unsigned)ul | ((unsigned)uh << 16);
}

// ---------------- prep: EB, WF + WEF (32x32 frags, K-scaled), POPK, out tail ----------------
__global__ void prep_kernel(const float* __restrict__ ent_table,
                            const float* __restrict__ op_table,
                            const float* __restrict__ non_table,
                            const float* __restrict__ Wm, const float* __restrict__ bm,
                            const float* __restrict__ Wg, const float* __restrict__ bg,
                            char* __restrict__ ws, float* __restrict__ out) {
    int idx = blockIdx.x * blockDim.x + threadIdx.x;
    if (idx < 800000) {                          // EB: ent_table -> f16, 8 elems/thread
        _Float16* EB = (_Float16*)(ws + OFF_EB);
        int base = idx * 8;
        const float4* s = (const float4*)(ent_table + base);
        float4 v0 = s[0], v1 = s[1];
        float xv[8] = {v0.x, v0.y, v0.z, v0.w, v1.x, v1.y, v1.z, v1.w};
        _Float16 h8[8];
        #pragma unroll
        for (int j = 0; j < 8; ++j) h8[j] = (_Float16)xv[j];
        *(f16x8*)(EB + base) = *(f16x8*)h8;
    } else if (idx < 832768) {                   // WF: 32x32 acc-path frags, K-scaled
        int e = idx - 800000;
        int jj = e & 7, l = (e >> 3) & 63, kt = (e >> 9) & 7, jb = e >> 12;
        int j = jb * 32 + (l & 31);
        int c = j >> 1, p = j & 1;
        int k = kt * 16 + (l >> 5) * 8 + jj;
        const float* Wrow = p ? (Wg + (size_t)c * 384) : (Wm + (size_t)c * 384);
        ((_Float16*)(ws + OFF_WF))[e] = (_Float16)(Wrow[256 + k] * (p ? KG : KM));
    } else if (idx < 865536) {                   // WEF: 32x32 ent-path frags, K-scaled
        int e = idx - 832768;
        int jj = e & 7, l = (e >> 3) & 63, kt = (e >> 9) & 7, jb = e >> 12;
        int j = jb * 32 + (l & 31);
        int c = j >> 1, p = j & 1;
        int k = kt * 16 + (l >> 5) * 8 + jj;
        const float* Wrow = p ? (Wg + (size_t)c * 384) : (Wm + (size_t)c * 384);
        ((_Float16*)(ws + OFF_WEF))[e] = (_Float16)(Wrow[128 + k] * (p ? KG : KM));
    } else if (idx < 866176) {                   // POPK: packed f16 {K*m, K*g} per u32
        int t2 = idx - 865536;
        int pr = t2 & 1, q = (t2 >> 1) & 3, h = (t2 >> 3) & 1, jb = (t2 >> 4) & 7, o = t2 >> 7;
        int j0 = jb * 32 + 8 * q + 4 * h + 2 * pr;
        int c = j0 >> 1;
        float sm = bm[c], sg = bg[c];
        const float* Wrm = Wm + (size_t)c * 384;
        const float* Wrg = Wg + (size_t)c * 384;
        for (int i = 0; i < 128; ++i) {
            float ov = op_table[o * HH + i];
            sm += ov * Wrm[i];
            sg += ov * Wrg[i];
        }
        ((unsigned*)(ws + OFF_POPK))[t2] = pk2rtn(sm * KM, sg * KG);
    } else if (idx < 866304) {
        int j = idx - 866176;
        out[(size_t)NROWS * HH + j] = non_table[j];
    }
}

// ---------------- fused chain: acc-MFMA + ent-MFMA (LDS-staged), no PEB ----------------
__global__ __launch_bounds__(512, 4)
void chain_kernel(const float* __restrict__ ent_table,
                  const int* __restrict__ ops_idx,
                  const int* __restrict__ ents_idx,
                  const int* __restrict__ left_idx,
                  const char* __restrict__ ws, float* __restrict__ out) {
    __shared__ char Abuf[2 * HALF];    // acc: [2p][32r][272B]
    __shared__ char Ebuf[2 * HALF];    // ent: [2p][32r][272B]
    __shared__ unsigned eo[17 * 32];   // [t][r]: (e<<9) | o
    __shared__ unsigned popk[640];

    const char* EBc = ws + OFF_EB;
    const f16x8* WFp = (const f16x8*)(ws + OFF_WF);
    const f16x8* WEFp = (const f16x8*)(ws + OFF_WEF);
    const unsigned* POPKg = (const unsigned*)(ws + OFF_POPK);

    int tid = threadIdx.x;
    int jb = tid >> 6, l = tid & 63, r = l & 31, h = l >> 5;
    int row0 = blockIdx.x * 32;

    for (int i = tid; i < 544; i += 512) {
        int t = i >> 5, rr = i & 31;
        unsigned e, o;
        if (t < 16) {
            e = ents_idx[(row0 + rr) * 17 + 15 - t];
            o = ops_idx[(row0 + rr) * 16 + 15 - t];
        } else {
            e = left_idx[row0 + rr];
            o = 4;
        }
        eo[i] = (e << 9) | o;
    }
    if (tid < 160) ((uint4*)popk)[tid] = ((const uint4*)POPKg)[tid];  // all 640 u32

    f16x8 WH[8], WE[8];
    #pragma unroll
    for (int kt = 0; kt < 8; ++kt) {
        WH[kt] = WFp[(jb * 8 + kt) * 64 + l];
        WE[kt] = WEFp[(jb * 8 + kt) * 64 + l];
    }

    int srr = tid >> 4, ssub = tid & 15;
    {   // acc0 init -> Abuf parity 0; ent(0) -> Ebuf parity 0
        int e = ents_idx[(row0 + srr) * 17 + 16];
        const float4* src = (const float4*)(ent_table + (size_t)e * HH + ssub * 8);
        float4 v0 = src[0], v1 = src[1];
        uint4 d;
        d.x = pk2(v0.x, v0.y); d.y = pk2(v0.z, v0.w);
        d.z = pk2(v1.x, v1.y); d.w = pk2(v1.z, v1.w);
        *(uint4*)(Abuf + srr * RSTR + ssub * 16) = d;
        int e0e = ents_idx[(row0 + srr) * 17 + 15];   // t=0 ent
        *(uint4*)(Ebuf + srr * RSTR + ssub * 16) =
            *(const uint4*)(EBc + (size_t)e0e * 256 + ssub * 16);
    }
    __syncthreads();

    int rb = r * RSTR + h * 16;              // B-frag read base (+ kt*32)
    int wb = r * RSTR + jb * 32 + h * 4;     // acc write base (+ q*8)
    const char* popkB = (const char*)popk + jb * 64 + h * 32;
    const unsigned* eoB = eo + r;

#define DO_STEP(T, RD, WR, FINAL)                                               \
    {                                                                           \
        uint4 sev;                                                              \
        if (!(FINAL)) {      /* stage ent(T+1): load now, ds_write after MFMA */\
            unsigned se = eo[((T) + 1) * 32 + srr] >> 9;                        \
            sev = *(const uint4*)(EBc + (size_t)se * 256 + ssub * 16);          \
        }                                                                       \
        unsigned va = eoB[(T) * 32];                                            \
        const char* pq = popkB + (va & 7u) * 512;                               \
        uint4 po0 = *(const uint4*)(pq);                                        \
        uint4 po1 = *(const uint4*)(pq + 16);                                   \
        unsigned po_u[8] = {po0.x, po0.y, po0.z, po0.w,                         \
                            po1.x, po1.y, po1.z, po1.w};                        \
        f32x16 C;                                                               \
        _Pragma("unroll")                                                       \
        for (int q = 0; q < 4; ++q)                                             \
            _Pragma("unroll")                                                   \
            for (int pr = 0; pr < 2; ++pr) {                                    \
                int u = q * 2 + pr;                                             \
                __half2 sb = *(const __half2*)&po_u[u];                         \
                C[4 * q + 2 * pr] = __low2float(sb);                            \
                C[4 * q + 2 * pr + 1] = __high2float(sb);                       \
            }                                                                   \
        _Pragma("unroll")                                                       \
        for (int kt = 0; kt < 8; ++kt) {                                        \
            f16x8 A = *(const f16x8*)(Abuf + rb + (RD) + kt * 32);              \
            C = __builtin_amdgcn_mfma_f32_32x32x16_f16(WH[kt], A, C, 0, 0, 0);  \
        }                                                                       \
        _Pragma("unroll")                                                       \
        for (int kt = 0; kt < 8; ++kt) {                                        \
            f16x8 A = *(const f16x8*)(Ebuf + rb + (RD) + kt * 32);              \
            C = __builtin_amdgcn_mfma_f32_32x32x16_f16(WE[kt], A, C, 0, 0, 0);  \
        }                                                                       \
        if (!(FINAL))                                                           \
            *(uint4*)(Ebuf + (WR) + srr * RSTR + ssub * 16) = sev;              \
        _Pragma("unroll")                                                       \
        for (int q = 0; q < 4; ++q) {                                           \
            float ov[2];                                                        \
            _Pragma("unroll")                                                   \
            for (int pr = 0; pr < 2; ++pr) {                                    \
                float m = C[4 * q + 2 * pr];                                    \
                float g = C[4 * q + 2 * pr + 1];                                \
                float em = FEXP2(m), eg = FEXP2(g);                             \
                ov[pr] = (em - 1.f) * __builtin_amdgcn_rcpf((em + 1.f) * (1.f + eg)); \
            }                                                                   \
            if (FINAL) {                                                        \
                *(float2*)(out + (size_t)(row0 + r) * HH + jb * 16 + 4 * q + 2 * h) \
                    = make_float2(ov[0], ov[1]);                                \
            } else {                                                            \
                *(unsigned*)(Abuf + wb + (WR) + q * 8) = pk2(ov[0], ov[1]);     \
            }                                                                   \
        }                                                                       \
        __syncthreads();                                                        \
    }

    for (int tb = 0; tb < 8; ++tb) {
        int t0 = 2 * tb;
        DO_STEP(t0, 0, HALF, 0)
        DO_STEP(t0 + 1, HALF, 0, 0)
    }
    DO_STEP(16, 0, HALF, 1)
#undef DO_STEP
}

extern "C" void kernel_launch(void* const* d_in, const int* in_sizes, int n_in,
                              void* d_out, int out_size, void* d_ws, size_t ws_size,
                              hipStream_t stream) {
    const float* ent_table = (const float*)d_in[0];
    const float* op_table  = (const float*)d_in[1];
    const float* non_table = (const float*)d_in[2];
    const float* Wm        = (const float*)d_in[3];
    const float* bm        = (const float*)d_in[4];
    const float* Wg        = (const float*)d_in[5];
    const float* bg        = (const float*)d_in[6];
    const int* ops_idx     = (const int*)d_in[7];
    const int* ents_idx    = (const int*)d_in[8];
    const int* left_idx    = (const int*)d_in[9];
    float* out = (float*)d_out;
    char* ws = (char*)d_ws;

    prep_kernel<<<3384, 256, 0, stream>>>(ent_table, op_table, non_table,
                                          Wm, bm, Wg, bg, ws, out);
    chain_kernel<<<NROWS / 32, 512, 0, stream>>>(ent_table, ops_idx, ents_idx,
                                                 left_idx, ws, out);
}

// Round 25
// 99.778 us; speedup vs baseline: 1.0429x; 1.0383x over previous
//
#include <hip/hip_runtime.h>
#include <hip/hip_bf16.h>
#include <hip/hip_fp16.h>

#define NROWS 32768
#define HH 128
#define ENTN 50000

typedef _Float16 f16x8 __attribute__((ext_vector_type(8)));
typedef __fp16 fp16x2 __attribute__((ext_vector_type(2)));
typedef float f32x4 __attribute__((ext_vector_type(4)));
typedef float f32x16 __attribute__((ext_vector_type(16)));

// ws byte offsets (no EB — pe converts f32 ent_table in-register)
#define OFF_PEB 0                       // u32 [50000][8jb][2h][4q][2pr] packed {f16 K*m | f16 K*g} (25.6 MB)
#define OFF_WF  25600000                // f16 [8jb][8kt][64][8] acc-weight frags, K-scaled (65536 B)
#define OFF_PEF (OFF_WF + 65536)        // f16 [16jbf][4kt][64][8] ent-weight frags, j-perm (65536 B)
#define OFF_POPK (OFF_PEF + 65536)      // u32 [5][8jb][2h][4q][2pr] packed f16 {K*m,K*g} (2560 B)

#define KM 2.8853901f
#define KG (-1.4426950f)
#define RSTR 272                        // acc LDS row stride (256 + 16 pad)
#define HALF (32 * RSTR)                // 8704 B per parity buffer
#define TILEB (2 * HALF)                // tile B base offset in Abuf

#if defined(__has_builtin)
#if __has_builtin(__builtin_amdgcn_exp2f)
#define FEXP2(x) __builtin_amdgcn_exp2f(x)
#endif
#endif
#ifndef FEXP2
__device__ __forceinline__ float __fexp2_asm(float x) {
    float r; asm("v_exp_f32 %0, %1" : "=v"(r) : "v"(x)); return r;
}
#define FEXP2(x) __fexp2_asm(x)
#endif

__device__ __forceinline__ unsigned pk2(float a, float b) {
    fp16x2 h = __builtin_amdgcn_cvt_pkrtz(a, b);
    unsigned u; __builtin_memcpy(&u, &h, 4); return u;
}
__device__ __forceinline__ unsigned pk2rtn(float a, float b) {
    _Float16 lo = (_Float16)a, hi = (_Float16)b;
    unsigned short ul, uh;
    __builtin_memcpy(&ul, &lo, 2); __builtin_memcpy(&uh, &hi, 2);
    return (unsigned)ul | ((unsigned)uh << 16);
}

// ---------------- prep (tiny): WF(32x32, K-scaled), PEF(j-perm), POPK, out tail ----------------
__global__ void prep_kernel(const float* __restrict__ op_table,
                            const float* __restrict__ non_table,
                            const float* __restrict__ Wm, const float* __restrict__ bm,
                            const float* __restrict__ Wg, const float* __restrict__ bg,
                            char* __restrict__ ws, float* __restrict__ out) {
    int idx = blockIdx.x * blockDim.x + threadIdx.x;
    if (idx < 32768) {                           // WF: 32x32 acc-path frags, K-scaled
        int e = idx;
        int jj = e & 7, l = (e >> 3) & 63, kt = (e >> 9) & 7, jb = e >> 12;
        int j = jb * 32 + (l & 31);
        int c = j >> 1, p = j & 1;
        int k = kt * 16 + (l >> 5) * 8 + jj;
        const float* Wrow = p ? (Wg + (size_t)c * 384) : (Wm + (size_t)c * 384);
        ((_Float16*)(ws + OFF_WF))[e] = (_Float16)(Wrow[256 + k] * (p ? KG : KM));
    } else if (idx < 65536) {                    // PEF: ent-path frags, j permuted for coalesced pe store
        int e = idx - 32768;
        int jj = e & 7, l = (e >> 3) & 63, kt = (e >> 9) & 3, jbf = e >> 11;
        int fr = l & 15;
        int j = (jbf >> 1) * 32 + 8 * (fr >> 2) + 4 * (jbf & 1) + (fr & 3);
        int c = j >> 1, p = j & 1;
        int k = kt * 32 + (l >> 4) * 8 + jj;
        const float* Wrow = p ? (Wg + (size_t)c * 384) : (Wm + (size_t)c * 384);
        ((_Float16*)(ws + OFF_PEF))[e] = (_Float16)Wrow[128 + k];
    } else if (idx < 66176) {                    // POPK: packed f16 {K*m, K*g} per u32
        int t2 = idx - 65536;
        int pr = t2 & 1, q = (t2 >> 1) & 3, h = (t2 >> 3) & 1, jb = (t2 >> 4) & 7, o = t2 >> 7;
        int j0 = jb * 32 + 8 * q + 4 * h + 2 * pr;  // even -> m col
        int c = j0 >> 1;
        float sm = bm[c], sg = bg[c];
        const float* Wrm = Wm + (size_t)c * 384;
        const float* Wrg = Wg + (size_t)c * 384;
        for (int i = 0; i < 128; ++i) {
            float ov = op_table[o * HH + i];
            sm += ov * Wrm[i];
            sg += ov * Wrg[i];
        }
        ((unsigned*)(ws + OFF_POPK))[t2] = pk2rtn(sm * KM, sg * KG);
    } else if (idx < 66304) {
        int j = idx - 66176;
        out[(size_t)NROWS * HH + j] = non_table[j];
    }
}

// ---------------- PEB = pack(K * (W_ent @ ent^T)): f32 source, coalesced remapped store ----------------
__global__ __launch_bounds__(256, 4)
void pe_kernel(const float* __restrict__ ent_table, char* __restrict__ ws) {
    const f16x8* PEF = (const f16x8*)(ws + OFF_PEF);
    char* PEB = ws + OFF_PEB;
    int tid = threadIdx.x, w = tid >> 6, l = tid & 63, lr = l & 15, lg = (l >> 4) & 3;
    int e0 = blockIdx.x * 32;

    f16x8 WB[4][4];
    #pragma unroll
    for (int u = 0; u < 4; ++u)
        #pragma unroll
        for (int kt = 0; kt < 4; ++kt)
            WB[u][kt] = PEF[((4 * w + u) * 4 + kt) * 64 + l];

    f32x4 C[2][4];
    #pragma unroll
    for (int rt = 0; rt < 2; ++rt)
        #pragma unroll
        for (int u = 0; u < 4; ++u) C[rt][u] = (f32x4){0.f, 0.f, 0.f, 0.f};

    #pragma unroll
    for (int kt = 0; kt < 4; ++kt) {
        #pragma unroll
        for (int rt = 0; rt < 2; ++rt) {
            int e = e0 + rt * 16 + lr;
            if (e >= ENTN) e = ENTN - 1;
            const float4* s = (const float4*)(ent_table + (size_t)e * HH + kt * 32 + lg * 8);
            float4 v0 = s[0], v1 = s[1];
            unsigned u4[4] = {pk2(v0.x, v0.y), pk2(v0.z, v0.w),
                              pk2(v1.x, v1.y), pk2(v1.z, v1.w)};
            f16x8 A; __builtin_memcpy(&A, u4, 16);
            #pragma unroll
            for (int u = 0; u < 4; ++u)
                C[rt][u] = __builtin_amdgcn_mfma_f32_16x16x32_f16(WB[u][kt], A, C[rt][u], 0, 0, 0);
        }
    }
    #pragma unroll
    for (int rt = 0; rt < 2; ++rt) {
        int e = e0 + rt * 16 + lr;
        if (e < ENTN) {
            #pragma unroll
            for (int u = 0; u < 4; ++u) {
                int jb2 = 2 * w + (u >> 1);
                uint2 st;
                st.x = pk2(C[rt][u][0] * KM, C[rt][u][1] * KG);
                st.y = pk2(C[rt][u][2] * KM, C[rt][u][3] * KG);
                *(uint2*)(PEB + (size_t)e * 512 + jb2 * 64 + (u & 1) * 32 + lg * 8) = st;
            }
        }
    }
}

// ---------------- fused 17-step chain: 32x32x16 MFMA, DUAL 32-row tiles per block ----------------
__global__ __launch_bounds__(512, 4)
void chain_kernel(const float* __restrict__ ent_table,
                  const int* __restrict__ ops_idx,
                  const int* __restrict__ ents_idx,
                  const int* __restrict__ left_idx,
                  const char* __restrict__ ws, float* __restrict__ out) {
    __shared__ char Abuf[4 * HALF];    // [2tile][2p][32r][272B]
    __shared__ unsigned eo[17 * 64];   // [t][rr]: (e<<9) | o, rr in 0..63
    __shared__ unsigned popk[640];

    const char* PEBc = ws + OFF_PEB;
    const f16x8* WFp = (const f16x8*)(ws + OFF_WF);
    const unsigned* POPKg = (const unsigned*)(ws + OFF_POPK);

    int tid = threadIdx.x;
    int jb = tid >> 6, l = tid & 63, r = l & 31, h = l >> 5;
    int row0 = blockIdx.x * 64;

    for (int i = tid; i < 17 * 64; i += 512) {
        int t = i >> 6, rr = i & 63;
        unsigned e, o;
        if (t < 16) {
            e = ents_idx[(row0 + rr) * 17 + 15 - t];
            o = ops_idx[(row0 + rr) * 16 + 15 - t];
        } else {
            e = left_idx[row0 + rr];
            o = 4;
        }
        eo[i] = (e << 9) | o;
    }
    for (int i = tid; i < 640; i += 512) popk[i] = POPKg[i];

    f16x8 WH[8];
    #pragma unroll
    for (int kt = 0; kt < 8; ++kt)
        WH[kt] = WFp[(jb * 8 + kt) * 64 + l];

    {   // acc0 init -> parity 0 of both tiles (64 rows, 8 threads/row, 32B f16 each)
        int rr = tid >> 3, sub = tid & 7;
        int e = ents_idx[(row0 + rr) * 17 + 16];
        const float4* src = (const float4*)(ent_table + (size_t)e * HH + sub * 16);
        float4 a = src[0], b = src[1], c2 = src[2], d2 = src[3];
        uint4 lo, hi;
        lo.x = pk2(a.x, a.y);  lo.y = pk2(a.z, a.w);
        lo.z = pk2(b.x, b.y);  lo.w = pk2(b.z, b.w);
        hi.x = pk2(c2.x, c2.y); hi.y = pk2(c2.z, c2.w);
        hi.z = pk2(d2.x, d2.y); hi.w = pk2(d2.z, d2.w);
        char* dst = Abuf + (rr >> 5) * TILEB + (rr & 31) * RSTR + sub * 32;
        *(uint4*)dst = lo;
        *(uint4*)(dst + 16) = hi;
    }
    __syncthreads();

    int rb = r * RSTR + h * 16;              // B-frag read base (+ kt*32)
    int wb = r * RSTR + jb * 32 + h * 4;     // acc write base (+ q*8)
    const char* pebBase = PEBc + jb * 64 + h * 32;
    const char* popkB = (const char*)popk + jb * 64 + h * 32;
    const unsigned* eoB = eo + r;

    unsigned vaA = eoB[0], vaB = eoB[32];
    uint4 pa0A = *(const uint4*)(pebBase + (vaA & 0xFFFFFE00u));
    uint4 pa1A = *(const uint4*)(pebBase + (vaA & 0xFFFFFE00u) + 16);
    uint4 pa0B = *(const uint4*)(pebBase + (vaB & 0xFFFFFE00u));
    uint4 pa1B = *(const uint4*)(pebBase + (vaB & 0xFFFFFE00u) + 16);

#define TILE_BODY(VA, PA0, PA1, TOFF, ROWOFF, RD, WR, FINAL)                    \
    {                                                                           \
        const char* pq = popkB + ((VA) & 7u) * 512;                             \
        uint4 po0 = *(const uint4*)(pq);                                        \
        uint4 po1 = *(const uint4*)(pq + 16);                                   \
        unsigned pe_u[8] = {(PA0).x, (PA0).y, (PA0).z, (PA0).w,                 \
                            (PA1).x, (PA1).y, (PA1).z, (PA1).w};                \
        unsigned po_u[8] = {po0.x, po0.y, po0.z, po0.w,                         \
                            po1.x, po1.y, po1.z, po1.w};                        \
        f32x16 C;                                                               \
        _Pragma("unroll")                                                       \
        for (int q = 0; q < 4; ++q)                                             \
            _Pragma("unroll")                                                   \
            for (int pr = 0; pr < 2; ++pr) {                                    \
                int u = q * 2 + pr;                                             \
                __half2 sa = *(const __half2*)&pe_u[u];                         \
                __half2 sb = *(const __half2*)&po_u[u];                         \
                __half2 s = __hadd2(sa, sb);                                    \
                C[4 * q + 2 * pr] = __low2float(s);                             \
                C[4 * q + 2 * pr + 1] = __high2float(s);                        \
            }                                                                   \
        _Pragma("unroll")                                                       \
        for (int kt = 0; kt < 8; ++kt) {                                        \
            f16x8 A = *(const f16x8*)(Abuf + (TOFF) + rb + (RD) + kt * 32);     \
            C = __builtin_amdgcn_mfma_f32_32x32x16_f16(WH[kt], A, C, 0, 0, 0);  \
        }                                                                       \
        _Pragma("unroll")                                                       \
        for (int q = 0; q < 4; ++q) {                                           \
            float ov[2];                                                        \
            _Pragma("unroll")                                                   \
            for (int pr = 0; pr < 2; ++pr) {                                    \
                float m = C[4 * q + 2 * pr];                                    \
                float g = C[4 * q + 2 * pr + 1];                                \
                float em = FEXP2(m), eg = FEXP2(g);                             \
                ov[pr] = (em - 1.f) * __builtin_amdgcn_rcpf((em + 1.f) * (1.f + eg)); \
            }                                                                   \
            if (FINAL) {                                                        \
                *(float2*)(out + (size_t)(row0 + (ROWOFF) + r) * HH             \
                           + jb * 16 + 4 * q + 2 * h) = make_float2(ov[0], ov[1]); \
            } else {                                                            \
                *(unsigned*)(Abuf + (TOFF) + wb + (WR) + q * 8) = pk2(ov[0], ov[1]); \
            }                                                                   \
        }                                                                       \
    }

#define DO_STEP(T, RD, WR, FINAL)                                               \
    {                                                                           \
        uint4 npa0A, npa1A, npa0B, npa1B; unsigned nvaA = 0, nvaB = 0;          \
        if (!(FINAL)) {                                                         \
            nvaA = eoB[((T) + 1) * 64];                                         \
            nvaB = eoB[((T) + 1) * 64 + 32];                                    \
            npa0A = *(const uint4*)(pebBase + (nvaA & 0xFFFFFE00u));            \
            npa1A = *(const uint4*)(pebBase + (nvaA & 0xFFFFFE00u) + 16);       \
            npa0B = *(const uint4*)(pebBase + (nvaB & 0xFFFFFE00u));            \
            npa1B = *(const uint4*)(pebBase + (nvaB & 0xFFFFFE00u) + 16);       \
        }                                                                       \
        TILE_BODY(vaA, pa0A, pa1A, 0, 0, RD, WR, FINAL)                         \
        TILE_BODY(vaB, pa0B, pa1B, TILEB, 32, RD, WR, FINAL)                    \
        __syncthreads();                                                        \
        if (!(FINAL)) {                                                         \
            pa0A = npa0A; pa1A = npa1A; vaA = nvaA;                             \
            pa0B = npa0B; pa1B = npa1B; vaB = nvaB;                             \
        }                                                                       \
    }

    for (int tb = 0; tb < 8; ++tb) {
        int t0 = 2 * tb;
        DO_STEP(t0, 0, HALF, 0)
        DO_STEP(t0 + 1, HALF, 0, 0)
    }
    DO_STEP(16, 0, HALF, 1)
#undef DO_STEP
#undef TILE_BODY
}

extern "C" void kernel_launch(void* const* d_in, const int* in_sizes, int n_in,
                              void* d_out, int out_size, void* d_ws, size_t ws_size,
                              hipStream_t stream) {
    const float* ent_table = (const float*)d_in[0];
    const float* op_table  = (const float*)d_in[1];
    const float* non_table = (const float*)d_in[2];
    const float* Wm        = (const float*)d_in[3];
    const float* bm        = (const float*)d_in[4];
    const float* Wg        = (const float*)d_in[5];
    const float* bg        = (const float*)d_in[6];
    const int* ops_idx     = (const int*)d_in[7];
    const int* ents_idx    = (const int*)d_in[8];
    const int* left_idx    = (const int*)d_in[9];
    float* out = (float*)d_out;
    char* ws = (char*)d_ws;

    prep_kernel<<<259, 256, 0, stream>>>(op_table, non_table, Wm, bm, Wg, bg, ws, out);
    pe_kernel<<<1563, 256, 0, stream>>>(ent_table, ws);
    chain_kernel<<<NROWS / 64, 512, 0, stream>>>(ent_table, ops_idx, ents_idx,
                                                 left_idx, ws, out);
}